// Round 9
// baseline (386.814 us; speedup 1.0000x reference)
//
#include <hip/hip_runtime.h>

#define S_  512
#define F_  64
#define H_  32
#define GQ  128   // 4*H
#define BT  4     // real batch rows per block
#define NB  512   // 2048/BT -> two blocks per CU

#define XS  72    // x plane row stride (ushorts): b128 quad-slots uniform
#define HS  40    // h plane row stride (ushorts): b128 quad-slots uniform
#define GS  33    // head buffer row stride (floats)

typedef __attribute__((ext_vector_type(8))) short bf16x8;
typedef __attribute__((ext_vector_type(4))) float f32x4;

// f32 -> (bf16_hi << 16) | bf16_lo, both RNE; f ~= hi + lo with ~2^-17 rel err
__device__ __forceinline__ unsigned pack_split(float f) {
    unsigned u  = __builtin_bit_cast(unsigned, f);
    unsigned hi = (u + 0x7FFFu + ((u >> 16) & 1u)) & 0xFFFF0000u;
    float    fl = f - __builtin_bit_cast(float, hi);
    unsigned ul = __builtin_bit_cast(unsigned, fl);
    unsigned lo = (ul + 0x7FFFu + ((ul >> 16) & 1u)) >> 16;
    return hi | lo;
}

__device__ __forceinline__ float sigm(float z) {
    return __builtin_amdgcn_rcpf(1.0f + __expf(-z));
}
__device__ __forceinline__ float tanh_f(float z) {
    return 2.0f * __builtin_amdgcn_rcpf(1.0f + __expf(-2.0f * z)) - 1.0f;
}

#define MFMA(A, B, C) __builtin_amdgcn_mfma_f32_16x16x32_bf16(A, B, C, 0, 0, 0)

// Transposed MFMA: A = weight cols (regs), B = x/h (LDS).
// Lane (c16, kg) of wave w owns all 4 gates of cell (batch=c16, unit jj=4w+kg).
__global__ __launch_bounds__(512, 1)
void lstm_mfma_kernel(const float* __restrict__ x,  const float* __restrict__ Wx,
                      const float* __restrict__ Wh, const float* __restrict__ bg,
                      const float* __restrict__ W1, const float* __restrict__ b1,
                      const float* __restrict__ W2, const float* __restrict__ b2,
                      const float* __restrict__ Wo, const float* __restrict__ bo,
                      float* __restrict__ out)
{
    const int tid = threadIdx.x;     // 0..511
    const int w   = tid >> 6;        // wave id
    const int L   = tid & 63;
    const int c16 = L & 15;          // A row / B col (batch) / D col
    const int kg  = L >> 4;          // k-group AND unit-offset of D rows
    const int bb  = blockIdx.x * BT;
    const int jj  = (w << 2) + kg;   // hidden unit owned by this lane

    // A row m=c16 corresponds to original weight column:
    const int gcol = ((c16 & 3) << 5) + (w << 2) + (c16 >> 2);

    __shared__ __align__(16) unsigned short xh[4][16][XS], xl[4][16][XS];
    __shared__ __align__(16) unsigned short hh[2][16][HS], hl[2][16][HS];
    __shared__ float Hd[3][BT][GS];

    // ---- A fragments: weight columns, split hi/lo (once) ----
    bf16x8 wx0h, wx0l, wx1h, wx1l, whh_, whl_;
#pragma unroll
    for (int i = 0; i < 8; ++i) {
        unsigned p = pack_split(Wx[(kg * 8 + i) * GQ + gcol]);
        wx0h[i] = (short)(unsigned short)(p >> 16);
        wx0l[i] = (short)(unsigned short)(p & 0xFFFFu);
        p = pack_split(Wx[(32 + kg * 8 + i) * GQ + gcol]);
        wx1h[i] = (short)(unsigned short)(p >> 16);
        wx1l[i] = (short)(unsigned short)(p & 0xFFFFu);
        p = pack_split(Wh[(kg * 8 + i) * GQ + gcol]);
        whh_[i] = (short)(unsigned short)(p >> 16);
        whl_[i] = (short)(unsigned short)(p & 0xFFFFu);
    }
    // bias for D row 4kg+r = gate r of unit jj
    f32x4 biasC;
#pragma unroll
    for (int r = 0; r < 4; ++r) biasC[r] = bg[r * 32 + jj];

    // ---- zero-init: x rows BT..15 (all slots); h both parity planes ----
    for (int i = tid; i < 4 * (16 - BT) * (XS / 2); i += 512) {
        int slot = i / ((16 - BT) * (XS / 2));
        int rem  = i - slot * (16 - BT) * (XS / 2);
        int row  = BT + rem / (XS / 2);
        int col  = rem % (XS / 2);
        ((unsigned*)&xh[slot][row][0])[col] = 0u;
        ((unsigned*)&xl[slot][row][0])[col] = 0u;
    }
    for (int i = tid; i < 2 * 16 * (HS / 2); i += 512) {
        ((unsigned*)&hh[0][0][0])[i] = 0u;
        ((unsigned*)&hl[0][0][0])[i] = 0u;
    }

    // x staging: threads 0..255 cover (row pr, feature pc), one float per step
    const bool stager = (tid < 256);
    const int pr = (tid >> 6) & 3;   // batch row 0..3
    const int pc = tid & 63;         // feature
    const float* xsrc = x + (size_t)(bb + pr) * S_ * F_ + pc;
    if (stager) {
#pragma unroll
        for (int tt = 0; tt < 2; ++tt) {
            unsigned p = pack_split(xsrc[(size_t)tt * F_]);
            xh[tt][pr][pc] = (unsigned short)(p >> 16);
            xl[tt][pr][pc] = (unsigned short)(p & 0xFFFFu);
        }
    }
    __syncthreads();

    float cc = 0.0f;

    for (int t = 0; t < S_; ++t) {
        // ---- pre-barrier: x work (slot t&3 published >=1 barrier ago) ----
        const int xs = t & 3;
        bf16x8 bx0h = *(const bf16x8*)&xh[xs][c16][kg * 8];
        bf16x8 bx0l = *(const bf16x8*)&xl[xs][c16][kg * 8];
        bf16x8 bx1h = *(const bf16x8*)&xh[xs][c16][32 + kg * 8];
        bf16x8 bx1l = *(const bf16x8*)&xl[xs][c16][32 + kg * 8];

        float xnf = 0.0f;
        const bool doPre = stager && (t + 2 < S_);
        if (doPre) xnf = xsrc[(size_t)(t + 2) * F_];   // early HBM issue

        f32x4 a0 = biasC;
        f32x4 a1 = { 0.0f, 0.0f, 0.0f, 0.0f };
        f32x4 a2 = { 0.0f, 0.0f, 0.0f, 0.0f };
        a0 = MFMA(wx0h, bx0h, a0);
        a1 = MFMA(wx0h, bx0l, a1);
        a2 = MFMA(wx0l, bx0h, a2);
        a0 = MFMA(wx1h, bx1h, a0);
        a1 = MFMA(wx1h, bx1l, a1);
        a2 = MFMA(wx1l, bx1h, a2);

        __syncthreads();   // h(t-1) published by all waves

        // ---- post-barrier: h chain ----
        const int hp = (t & 1) ^ 1;
        bf16x8 bhh = *(const bf16x8*)&hh[hp][c16][kg * 8];
        bf16x8 bhl = *(const bf16x8*)&hl[hp][c16][kg * 8];
        a0 = MFMA(whh_, bhh, a0);
        a1 = MFMA(whh_, bhl, a1);
        a2 = MFMA(whl_, bhh, a2);
        f32x4 z = (a0 + a1) + a2;

        // gates: in-lane, static per register index
        float iv = sigm(z[0]);
        float fv = sigm(z[1]);
        float gv = tanh_f(z[2]);
        float ov = sigm(z[3]);
        cc = fmaf(fv, cc, iv * gv);
        float hv = ov * tanh_f(cc);

        const int wp = t & 1;
        unsigned p = pack_split(hv);
        hh[wp][c16][jj] = (unsigned short)(p >> 16);
        hl[wp][c16][jj] = (unsigned short)(p & 0xFFFFu);
        if (t == S_ - 1 && c16 < BT) Hd[0][c16][jj] = hv;

        // pack + publish x[t+2] (slot (t+2)&3; readers >=1 barrier away)
        if (doPre) {
            unsigned q = pack_split(xnf);
            const int s2 = (t + 2) & 3;
            xh[s2][pr][pc] = (unsigned short)(q >> 16);
            xl[s2][pr][pc] = (unsigned short)(q & 0xFFFFu);
        }
    }
    __syncthreads();

    // ---- MLP head: 32 -> 32 -> 16 -> 3, leaky_relu(0.01) ----
    if (tid < BT * 32) {
        int rb = tid >> 5, n = tid & 31;
        float a = b1[n];
#pragma unroll
        for (int k = 0; k < 32; ++k) a = fmaf(Hd[0][rb][k], W1[k * 32 + n], a);
        a = (a > 0.0f) ? a : 0.01f * a;
        Hd[1][rb][n] = a;
    }
    __syncthreads();
    if (tid < BT * 16) {
        int rb = tid >> 4, n = tid & 15;
        float a = b2[n];
#pragma unroll
        for (int k = 0; k < 32; ++k) a = fmaf(Hd[1][rb][k], W2[k * 16 + n], a);
        a = (a > 0.0f) ? a : 0.01f * a;
        Hd[2][rb][n] = a;
    }
    __syncthreads();
    if (tid < BT * 3) {
        int rb = tid / 3, n = tid - rb * 3;
        float a = bo[n];
#pragma unroll
        for (int k = 0; k < 16; ++k) a = fmaf(Hd[2][rb][k], Wo[k * 3 + n], a);
        out[(size_t)(bb + rb) * 3 + n] = a;
    }
}

extern "C" void kernel_launch(void* const* d_in, const int* in_sizes, int n_in,
                              void* d_out, int out_size, void* d_ws, size_t ws_size,
                              hipStream_t stream) {
    const float* x  = (const float*)d_in[0];
    const float* Wx = (const float*)d_in[1];
    const float* Wh = (const float*)d_in[2];
    const float* bg = (const float*)d_in[3];
    const float* W1 = (const float*)d_in[4];
    const float* b1 = (const float*)d_in[5];
    const float* W2 = (const float*)d_in[6];
    const float* b2 = (const float*)d_in[7];
    const float* Wo = (const float*)d_in[8];
    const float* bo = (const float*)d_in[9];
    float* out = (float*)d_out;

    hipLaunchKernelGGL(lstm_mfma_kernel, dim3(NB), dim3(512), 0, stream,
                       x, Wx, Wh, bg, W1, b1, W2, b2, Wo, bo, out);
}

// Round 10
// 230.746 us; speedup vs baseline: 1.6764x; 1.6764x over previous
//
#include <hip/hip_runtime.h>

#define S_  512
#define F_  64
#define H_  32
#define GQ  128   // 4*H
#define BT  8     // real batch rows per block
#define NB  256   // 2048/BT -> one block per CU

#define XS  72    // x plane row stride (ushorts)
#define HS  40    // h plane row stride (ushorts)
#define GS  33    // head buffer row stride (floats)

typedef __attribute__((ext_vector_type(8))) short bf16x8;
typedef __attribute__((ext_vector_type(4))) float f32x4;

// f32 -> (bf16_hi << 16) | bf16_lo, both RNE; f ~= hi + lo with ~2^-17 rel err
__device__ __forceinline__ unsigned pack_split(float f) {
    unsigned u  = __builtin_bit_cast(unsigned, f);
    unsigned hi = (u + 0x7FFFu + ((u >> 16) & 1u)) & 0xFFFF0000u;
    float    fl = f - __builtin_bit_cast(float, hi);
    unsigned ul = __builtin_bit_cast(unsigned, fl);
    unsigned lo = (ul + 0x7FFFu + ((ul >> 16) & 1u)) >> 16;
    return hi | lo;
}

__device__ __forceinline__ float sigm(float z) {
    return __builtin_amdgcn_rcpf(1.0f + __expf(-z));
}
__device__ __forceinline__ float tanh_f(float z) {
    return 2.0f * __builtin_amdgcn_rcpf(1.0f + __expf(-2.0f * z)) - 1.0f;
}

#define MFMA(A, B, C) __builtin_amdgcn_mfma_f32_16x16x32_bf16(A, B, C, 0, 0, 0)

// Transposed MFMA, time-packed: A = weight cols (regs), B cols = batch(0..7) + 8*dt.
// One x-GEMM pass serves timesteps t and t+1; h-part runs per-step.
// Lane (c16, kg) of wave w owns all 4 gates of cell (batch=c16, unit jj=4w+kg), c16<8.
__global__ __launch_bounds__(512, 1)
void lstm_mfma_kernel(const float* __restrict__ x,  const float* __restrict__ Wx,
                      const float* __restrict__ Wh, const float* __restrict__ bg,
                      const float* __restrict__ W1, const float* __restrict__ b1,
                      const float* __restrict__ W2, const float* __restrict__ b2,
                      const float* __restrict__ Wo, const float* __restrict__ bo,
                      float* __restrict__ out)
{
    const int tid = threadIdx.x;     // 0..511
    const int w   = tid >> 6;        // wave id
    const int L   = tid & 63;
    const int c16 = L & 15;          // B col: batch(0..7) + 8*dt / D col
    const int kg  = L >> 4;          // k-group AND unit-offset of D rows
    const int bb  = blockIdx.x * BT;
    const int jj  = (w << 2) + kg;   // hidden unit owned by this lane

    // A row m -> weight column: gcol(m) = (m&3)*32 + 4w + (m>>2)
    const int gcol = ((c16 & 3) << 5) + (w << 2) + (c16 >> 2);

    __shared__ __align__(16) unsigned short xh[4][16][XS], xl[4][16][XS];
    __shared__ __align__(16) unsigned short hh[2][16][HS], hl[2][16][HS];
    __shared__ float Hd[3][BT][GS];

    // ---- A fragments: weight columns, split hi/lo (once) ----
    bf16x8 wx0h, wx0l, wx1h, wx1l, whh_, whl_;
#pragma unroll
    for (int i = 0; i < 8; ++i) {
        unsigned p = pack_split(Wx[(kg * 8 + i) * GQ + gcol]);
        wx0h[i] = (short)(unsigned short)(p >> 16);
        wx0l[i] = (short)(unsigned short)(p & 0xFFFFu);
        p = pack_split(Wx[(32 + kg * 8 + i) * GQ + gcol]);
        wx1h[i] = (short)(unsigned short)(p >> 16);
        wx1l[i] = (short)(unsigned short)(p & 0xFFFFu);
        p = pack_split(Wh[(kg * 8 + i) * GQ + gcol]);
        whh_[i] = (short)(unsigned short)(p >> 16);
        whl_[i] = (short)(unsigned short)(p & 0xFFFFu);
    }
    f32x4 biasC;
#pragma unroll
    for (int r = 0; r < 4; ++r) biasC[r] = bg[r * 32 + jj];

    // ---- zero h planes (rows 8..15 stay zero forever) ----
    for (int i = tid; i < 2 * 16 * (HS / 2); i += 512) {
        ((unsigned*)&hh[0][0][0])[i] = 0u;
        ((unsigned*)&hl[0][0][0])[i] = 0u;
    }

    // x staging map: row = batch(0..7) + 8*dt, feature pair
    const int srow = tid >> 5;       // 0..15
    const int sfp  = tid & 31;       // feature pair 0..31
    const int sdt  = srow >> 3;      // dt 0/1
    const float* xsrc = x + (size_t)(bb + (srow & 7)) * S_ * F_ + 2 * sfp;

    // prologue: stage td=0,1; prefetch td=2,3 into named regs
    {
        float2 v0 = *(const float2*)(xsrc + (size_t)(0 + sdt) * F_);
        float2 v1 = *(const float2*)(xsrc + (size_t)(2 + sdt) * F_);
        unsigned p0 = pack_split(v0.x), p1 = pack_split(v0.y);
        *(unsigned*)&xh[0][srow][2 * sfp] = (p0 >> 16) | (p1 & 0xFFFF0000u);
        *(unsigned*)&xl[0][srow][2 * sfp] = (p0 & 0xFFFFu) | (p1 << 16);
        p0 = pack_split(v1.x); p1 = pack_split(v1.y);
        *(unsigned*)&xh[1][srow][2 * sfp] = (p0 >> 16) | (p1 & 0xFFFF0000u);
        *(unsigned*)&xl[1][srow][2 * sfp] = (p0 & 0xFFFFu) | (p1 << 16);
    }
    float2 xvA = *(const float2*)(xsrc + (size_t)(4 + sdt) * F_);
    float2 xvB = *(const float2*)(xsrc + (size_t)(6 + sdt) * F_);
    __syncthreads();

    float cc = 0.0f;

#define DSTEP(TD, XV)                                                          \
    {                                                                          \
        const int td = (TD);                                                   \
        const int xslot = td & 3;                                              \
        /* phase 1: step t = 2*td (h[t-1] in plane 1) */                       \
        bf16x8 bx0h = *(const bf16x8*)&xh[xslot][c16][kg * 8];                 \
        bf16x8 bx0l = *(const bf16x8*)&xl[xslot][c16][kg * 8];                 \
        bf16x8 bx1h = *(const bf16x8*)&xh[xslot][c16][32 + kg * 8];            \
        bf16x8 bx1l = *(const bf16x8*)&xl[xslot][c16][32 + kg * 8];            \
        bf16x8 bhh = *(const bf16x8*)&hh[1][c16][kg * 8];                      \
        bf16x8 bhl = *(const bf16x8*)&hl[1][c16][kg * 8];                      \
        f32x4 a0 = biasC;                                                      \
        f32x4 a1 = {0.f, 0.f, 0.f, 0.f};                                       \
        f32x4 a2 = {0.f, 0.f, 0.f, 0.f};                                       \
        a0 = MFMA(wx0h, bx0h, a0); a1 = MFMA(wx0h, bx0l, a1);                  \
        a2 = MFMA(wx0l, bx0h, a2);                                             \
        a0 = MFMA(wx1h, bx1h, a0); a1 = MFMA(wx1h, bx1l, a1);                  \
        a2 = MFMA(wx1l, bx1h, a2);                                             \
        f32x4 xs = (a0 + a1) + a2;        /* bias + x, both times */           \
        f32x4 xz1;                                                             \
        xz1[0] = __shfl_xor(xs[0], 8); xz1[1] = __shfl_xor(xs[1], 8);          \
        xz1[2] = __shfl_xor(xs[2], 8); xz1[3] = __shfl_xor(xs[3], 8);          \
        a0 = MFMA(whh_, bhh, a0); a1 = MFMA(whh_, bhl, a1);                    \
        a2 = MFMA(whl_, bhh, a2);                                              \
        f32x4 z = (a0 + a1) + a2;                                              \
        float iv = sigm(z[0]), fv = sigm(z[1]);                                \
        float gv = tanh_f(z[2]), ov = sigm(z[3]);                              \
        cc = fmaf(fv, cc, iv * gv);                                            \
        float hv = ov * tanh_f(cc);                                            \
        if (c16 < 8) {                                                         \
            unsigned p = pack_split(hv);                                       \
            hh[0][c16][jj] = (unsigned short)(p >> 16);                        \
            hl[0][c16][jj] = (unsigned short)(p & 0xFFFFu);                    \
        }                                                                      \
        __syncthreads();   /* A: h[t] visible */                               \
        /* phase 2: step t+1 (h[t] in plane 0) */                              \
        bhh = *(const bf16x8*)&hh[0][c16][kg * 8];                             \
        bhl = *(const bf16x8*)&hl[0][c16][kg * 8];                             \
        a0 = xz1;                                                              \
        a1 = (f32x4){0.f, 0.f, 0.f, 0.f};                                      \
        a2 = (f32x4){0.f, 0.f, 0.f, 0.f};                                      \
        a0 = MFMA(whh_, bhh, a0); a1 = MFMA(whh_, bhl, a1);                    \
        a2 = MFMA(whl_, bhh, a2);                                              \
        z = (a0 + a1) + a2;                                                    \
        iv = sigm(z[0]); fv = sigm(z[1]);                                      \
        gv = tanh_f(z[2]); ov = sigm(z[3]);                                    \
        cc = fmaf(fv, cc, iv * gv);                                            \
        hv = ov * tanh_f(cc);                                                  \
        if (c16 < 8) {                                                         \
            unsigned p = pack_split(hv);                                       \
            hh[1][c16][jj] = (unsigned short)(p >> 16);                        \
            hl[1][c16][jj] = (unsigned short)(p & 0xFFFFu);                    \
        }                                                                      \
        if (td == 255 && c16 < 8) Hd[0][c16][jj] = hv;                         \
        {   /* stage x for td+2; reload for td+4 */                            \
            unsigned p0 = pack_split(XV.x), p1 = pack_split(XV.y);             \
            const int s2 = (td + 2) & 3;                                       \
            *(unsigned*)&xh[s2][srow][2 * sfp] = (p0 >> 16) | (p1 & 0xFFFF0000u); \
            *(unsigned*)&xl[s2][srow][2 * sfp] = (p0 & 0xFFFFu) | (p1 << 16);  \
            int tl = td + 4; if (tl > 255) tl = 255;                           \
            XV = *(const float2*)(xsrc + (size_t)(2 * tl + sdt) * F_);         \
        }                                                                      \
        __syncthreads();   /* B: h[t+1] + staged x visible */                  \
    }

    for (int qd = 0; qd < 128; ++qd) {
        DSTEP(2 * qd,     xvA)
        DSTEP(2 * qd + 1, xvB)
    }
#undef DSTEP

    // ---- MLP head: 32 -> 32 -> 16 -> 3, leaky_relu(0.01) ----
    if (tid < 256) {
        int rb = tid >> 5, n = tid & 31;
        float a = b1[n];
#pragma unroll
        for (int k = 0; k < 32; ++k) a = fmaf(Hd[0][rb][k], W1[k * 32 + n], a);
        a = (a > 0.0f) ? a : 0.01f * a;
        Hd[1][rb][n] = a;
    }
    __syncthreads();
    if (tid < 128) {
        int rb = tid >> 4, n = tid & 15;
        float a = b2[n];
#pragma unroll
        for (int k = 0; k < 32; ++k) a = fmaf(Hd[1][rb][k], W2[k * 16 + n], a);
        a = (a > 0.0f) ? a : 0.01f * a;
        Hd[2][rb][n] = a;
    }
    __syncthreads();
    if (tid < 24) {
        int rb = tid / 3, n = tid - rb * 3;
        float a = bo[n];
#pragma unroll
        for (int k = 0; k < 16; ++k) a = fmaf(Hd[2][rb][k], Wo[k * 3 + n], a);
        out[(size_t)(bb + rb) * 3 + n] = a;
    }
}

extern "C" void kernel_launch(void* const* d_in, const int* in_sizes, int n_in,
                              void* d_out, int out_size, void* d_ws, size_t ws_size,
                              hipStream_t stream) {
    const float* x  = (const float*)d_in[0];
    const float* Wx = (const float*)d_in[1];
    const float* Wh = (const float*)d_in[2];
    const float* bg = (const float*)d_in[3];
    const float* W1 = (const float*)d_in[4];
    const float* b1 = (const float*)d_in[5];
    const float* W2 = (const float*)d_in[6];
    const float* b2 = (const float*)d_in[7];
    const float* Wo = (const float*)d_in[8];
    const float* bo = (const float*)d_in[9];
    float* out = (float*)d_out;

    hipLaunchKernelGGL(lstm_mfma_kernel, dim3(NB), dim3(512), 0, stream,
                       x, Wx, Wh, bg, W1, b1, W2, b2, Wo, bo, out);
}

// Round 11
// 218.423 us; speedup vs baseline: 1.7709x; 1.0564x over previous
//
#include <hip/hip_runtime.h>

#define S_  512
#define F_  64
#define H_  32
#define GQ  128   // 4*H
#define BT  8     // real batch rows per block
#define NB  256   // 2048/BT -> one block per CU

#define XS  72    // x plane row stride (ushorts)
#define HS  40    // h plane row stride (ushorts)
#define ZS  20    // xz plane row stride (floats): (5*row+kg)&7 uniform
#define GS  33    // head buffer row stride (floats)

typedef __attribute__((ext_vector_type(8))) short bf16x8;
typedef __attribute__((ext_vector_type(4))) float f32x4;

// f32 -> (bf16_hi << 16) | bf16_lo, both RNE; f ~= hi + lo with ~2^-17 rel err
__device__ __forceinline__ unsigned pack_split(float f) {
    unsigned u  = __builtin_bit_cast(unsigned, f);
    unsigned hi = (u + 0x7FFFu + ((u >> 16) & 1u)) & 0xFFFF0000u;
    float    fl = f - __builtin_bit_cast(float, hi);
    unsigned ul = __builtin_bit_cast(unsigned, fl);
    unsigned lo = (ul + 0x7FFFu + ((ul >> 16) & 1u)) >> 16;
    return hi | lo;
}

__device__ __forceinline__ float sigm(float z) {
    return __builtin_amdgcn_rcpf(1.0f + __expf(-z));
}
__device__ __forceinline__ float tanh_f(float z) {
    return 2.0f * __builtin_amdgcn_rcpf(1.0f + __expf(-2.0f * z)) - 1.0f;
}

#define MFMA(A, B, C) __builtin_amdgcn_mfma_f32_16x16x32_bf16(A, B, C, 0, 0, 0)

// Producer-consumer: waves 0-7 (rec) run the h-recurrence; waves 8-15 (helpers)
// stage/pack x and produce xz = bias + x@Wx one DSTEP ahead into xzg.
// Time-packed cols: B col = batch(0..7) + 8*dt. Rec lane (c16,kg) of wave w owns
// all 4 gates of cell (batch c16, unit jj=4w+kg), active c16<8.
__global__ __launch_bounds__(1024, 1)
void lstm_mfma_kernel(const float* __restrict__ x,  const float* __restrict__ Wx,
                      const float* __restrict__ Wh, const float* __restrict__ bg,
                      const float* __restrict__ W1, const float* __restrict__ b1,
                      const float* __restrict__ W2, const float* __restrict__ b2,
                      const float* __restrict__ Wo, const float* __restrict__ bo,
                      float* __restrict__ out)
{
    const int tid = threadIdx.x;     // 0..1023
    const int w   = tid >> 6;        // wave id 0..15
    const int L   = tid & 63;
    const int c16 = L & 15;          // B col: batch(0..7) + 8*dt / D col
    const int kg  = L >> 4;          // k-group AND unit-offset of D rows
    const int bb  = blockIdx.x * BT;
    const bool isRec = (w < 8);
    const int g   = w & 7;           // gate group (rec: consumes; helper: produces)
    const int jj  = (g << 2) + kg;   // hidden unit owned (rec lanes)

    // A row m -> weight column: gcol(m) = (m&3)*32 + 4g + (m>>2)
    const int gcol = ((c16 & 3) << 5) + (g << 2) + (c16 >> 2);

    __shared__ __align__(16) unsigned short xh[4][16][XS], xl[4][16][XS];
    __shared__ __align__(16) unsigned short hh[2][16][HS], hl[2][16][HS];
    __shared__ __align__(16) float xzg[2][8][16][ZS];   // xz per group, dbuf
    __shared__ float Hd[3][BT][GS];

    // ---- role-specific register-resident weights ----
    bf16x8 whh_ = {0,0,0,0,0,0,0,0}, whl_ = {0,0,0,0,0,0,0,0};
    bf16x8 wx0h = {0,0,0,0,0,0,0,0}, wx0l = {0,0,0,0,0,0,0,0};
    bf16x8 wx1h = {0,0,0,0,0,0,0,0}, wx1l = {0,0,0,0,0,0,0,0};
    f32x4 biasC = {0.f, 0.f, 0.f, 0.f};
    if (isRec) {
#pragma unroll
        for (int i = 0; i < 8; ++i) {
            unsigned p = pack_split(Wh[(kg * 8 + i) * GQ + gcol]);
            whh_[i] = (short)(unsigned short)(p >> 16);
            whl_[i] = (short)(unsigned short)(p & 0xFFFFu);
        }
    } else {
#pragma unroll
        for (int i = 0; i < 8; ++i) {
            unsigned p = pack_split(Wx[(kg * 8 + i) * GQ + gcol]);
            wx0h[i] = (short)(unsigned short)(p >> 16);
            wx0l[i] = (short)(unsigned short)(p & 0xFFFFu);
            p = pack_split(Wx[(32 + kg * 8 + i) * GQ + gcol]);
            wx1h[i] = (short)(unsigned short)(p >> 16);
            wx1l[i] = (short)(unsigned short)(p & 0xFFFFu);
        }
#pragma unroll
        for (int r = 0; r < 4; ++r) biasC[r] = bg[r * 32 + jj];
    }

    // ---- zero h planes (rows 8..15 stay zero forever) ----
    for (int i = tid; i < 2 * 16 * (HS / 2); i += 1024) {
        ((unsigned*)&hh[0][0][0])[i] = 0u;
        ((unsigned*)&hl[0][0][0])[i] = 0u;
    }

    // helper staging map: row = batch(0..7) + 8*dt, feature pair
    const int hu   = tid & 511;
    const int srow = hu >> 5;        // 0..15
    const int sfp  = hu & 31;        // feature pair
    const int sdt  = srow >> 3;      // dt 0/1
    const float* xsrc = x + (size_t)(bb + (srow & 7)) * S_ * F_ + 2 * sfp;
    float2 xvA = {0.f, 0.f}, xvB = {0.f, 0.f};
    if (!isRec) {
        float2 v0 = *(const float2*)(xsrc + (size_t)(0 + sdt) * F_);
        float2 v1 = *(const float2*)(xsrc + (size_t)(2 + sdt) * F_);
        unsigned p0 = pack_split(v0.x), p1 = pack_split(v0.y);
        *(unsigned*)&xh[0][srow][2 * sfp] = (p0 >> 16) | (p1 & 0xFFFF0000u);
        *(unsigned*)&xl[0][srow][2 * sfp] = (p0 & 0xFFFFu) | (p1 << 16);
        p0 = pack_split(v1.x); p1 = pack_split(v1.y);
        *(unsigned*)&xh[1][srow][2 * sfp] = (p0 >> 16) | (p1 & 0xFFFF0000u);
        *(unsigned*)&xl[1][srow][2 * sfp] = (p0 & 0xFFFFu) | (p1 << 16);
        xvA = *(const float2*)(xsrc + (size_t)(4 + sdt) * F_);
        xvB = *(const float2*)(xsrc + (size_t)(6 + sdt) * F_);
    }
    __syncthreads();

#define XGEMM(XSLOT, ZSLOT) {                                                  \
        const int xs_ = (XSLOT);                                               \
        bf16x8 bx0h = *(const bf16x8*)&xh[xs_][c16][kg * 8];                   \
        bf16x8 bx0l = *(const bf16x8*)&xl[xs_][c16][kg * 8];                   \
        bf16x8 bx1h = *(const bf16x8*)&xh[xs_][c16][32 + kg * 8];              \
        bf16x8 bx1l = *(const bf16x8*)&xl[xs_][c16][32 + kg * 8];              \
        f32x4 a1 = {0.f, 0.f, 0.f, 0.f};                                       \
        f32x4 a2 = {0.f, 0.f, 0.f, 0.f};                                       \
        f32x4 a0 = MFMA(wx0h, bx0h, biasC);                                    \
        a1 = MFMA(wx0h, bx0l, a1);                                             \
        a2 = MFMA(wx0l, bx0h, a2);                                             \
        a0 = MFMA(wx1h, bx1h, a0);                                             \
        a1 = MFMA(wx1h, bx1l, a1);                                             \
        a2 = MFMA(wx1l, bx1h, a2);                                             \
        f32x4 xz_ = (a0 + a1) + a2;                                            \
        *(f32x4*)&xzg[(ZSLOT)][g][c16][kg << 2] = xz_;                         \
    }

    // pre-loop: helpers produce xz[0]
    if (!isRec) XGEMM(0, 0)
    __syncthreads();

    float cc = 0.0f;

#define DSTEP(TD, XV) {                                                        \
    const int td = (TD);                                                       \
    f32x4 xz2 = {0.f, 0.f, 0.f, 0.f};                                          \
    if (isRec) {                                                               \
        f32x4 xzv = *(const f32x4*)&xzg[td & 1][g][c16][kg << 2];              \
        xz2 = *(const f32x4*)&xzg[td & 1][g][c16 ^ 8][kg << 2];                \
        bf16x8 bhh = *(const bf16x8*)&hh[1][c16][kg * 8];                      \
        bf16x8 bhl = *(const bf16x8*)&hl[1][c16][kg * 8];                      \
        f32x4 a1 = {0.f, 0.f, 0.f, 0.f};                                       \
        f32x4 a2 = {0.f, 0.f, 0.f, 0.f};                                       \
        f32x4 a0 = MFMA(whh_, bhh, xzv);                                       \
        a1 = MFMA(whh_, bhl, a1);                                              \
        a2 = MFMA(whl_, bhh, a2);                                              \
        f32x4 z = (a0 + a1) + a2;                                              \
        float iv = sigm(z[0]), fv = sigm(z[1]);                                \
        float gv = tanh_f(z[2]), ov = sigm(z[3]);                              \
        cc = fmaf(fv, cc, iv * gv);                                            \
        float hv = ov * tanh_f(cc);                                            \
        if (c16 < 8) {                                                         \
            unsigned p = pack_split(hv);                                       \
            hh[0][c16][jj] = (unsigned short)(p >> 16);                        \
            hl[0][c16][jj] = (unsigned short)(p & 0xFFFFu);                    \
        }                                                                      \
    } else {                                                                   \
        XGEMM((td + 1) & 3, (td + 1) & 1)                                      \
    }                                                                          \
    __syncthreads();   /* A: h[2td] + xz[td+1] visible */                      \
    if (isRec) {                                                               \
        bf16x8 bhh = *(const bf16x8*)&hh[0][c16][kg * 8];                      \
        bf16x8 bhl = *(const bf16x8*)&hl[0][c16][kg * 8];                      \
        f32x4 a1 = {0.f, 0.f, 0.f, 0.f};                                       \
        f32x4 a2 = {0.f, 0.f, 0.f, 0.f};                                       \
        f32x4 a0 = MFMA(whh_, bhh, xz2);                                       \
        a1 = MFMA(whh_, bhl, a1);                                              \
        a2 = MFMA(whl_, bhh, a2);                                              \
        f32x4 z = (a0 + a1) + a2;                                              \
        float iv = sigm(z[0]), fv = sigm(z[1]);                                \
        float gv = tanh_f(z[2]), ov = sigm(z[3]);                              \
        cc = fmaf(fv, cc, iv * gv);                                            \
        float hv = ov * tanh_f(cc);                                            \
        if (c16 < 8) {                                                         \
            unsigned p = pack_split(hv);                                       \
            hh[1][c16][jj] = (unsigned short)(p >> 16);                        \
            hl[1][c16][jj] = (unsigned short)(p & 0xFFFFu);                    \
            if (td == 255) Hd[0][c16][jj] = hv;                                \
        }                                                                      \
    } else {                                                                   \
        unsigned p0 = pack_split(XV.x), p1 = pack_split(XV.y);                 \
        const int s2 = (td + 2) & 3;                                           \
        *(unsigned*)&xh[s2][srow][2 * sfp] = (p0 >> 16) | (p1 & 0xFFFF0000u);  \
        *(unsigned*)&xl[s2][srow][2 * sfp] = (p0 & 0xFFFFu) | (p1 << 16);      \
        int tl = td + 4; if (tl > 255) tl = 255;                               \
        XV = *(const float2*)(xsrc + (size_t)(2 * tl + sdt) * F_);             \
    }                                                                          \
    __syncthreads();   /* B: h[2td+1] + staged x visible */                    \
}

    for (int qd = 0; qd < 128; ++qd) {
        DSTEP(2 * qd,     xvA)
        DSTEP(2 * qd + 1, xvB)
    }
#undef DSTEP
#undef XGEMM

    // ---- MLP head: 32 -> 32 -> 16 -> 3, leaky_relu(0.01) ----
    if (tid < 256) {
        int rb = tid >> 5, n = tid & 31;
        float a = b1[n];
#pragma unroll
        for (int k = 0; k < 32; ++k) a = fmaf(Hd[0][rb][k], W1[k * 32 + n], a);
        a = (a > 0.0f) ? a : 0.01f * a;
        Hd[1][rb][n] = a;
    }
    __syncthreads();
    if (tid < 128) {
        int rb = tid >> 4, n = tid & 15;
        float a = b2[n];
#pragma unroll
        for (int k = 0; k < 32; ++k) a = fmaf(Hd[1][rb][k], W2[k * 16 + n], a);
        a = (a > 0.0f) ? a : 0.01f * a;
        Hd[2][rb][n] = a;
    }
    __syncthreads();
    if (tid < 24) {
        int rb = tid / 3, n = tid - rb * 3;
        float a = bo[n];
#pragma unroll
        for (int k = 0; k < 16; ++k) a = fmaf(Hd[2][rb][k], Wo[k * 3 + n], a);
        out[(size_t)(bb + rb) * 3 + n] = a;
    }
}

extern "C" void kernel_launch(void* const* d_in, const int* in_sizes, int n_in,
                              void* d_out, int out_size, void* d_ws, size_t ws_size,
                              hipStream_t stream) {
    const float* x  = (const float*)d_in[0];
    const float* Wx = (const float*)d_in[1];
    const float* Wh = (const float*)d_in[2];
    const float* bg = (const float*)d_in[3];
    const float* W1 = (const float*)d_in[4];
    const float* b1 = (const float*)d_in[5];
    const float* W2 = (const float*)d_in[6];
    const float* b2 = (const float*)d_in[7];
    const float* Wo = (const float*)d_in[8];
    const float* bo = (const float*)d_in[9];
    float* out = (float*)d_out;

    hipLaunchKernelGGL(lstm_mfma_kernel, dim3(NB), dim3(1024), 0, stream,
                       x, Wx, Wh, bg, W1, b1, W2, b2, Wo, bo, out);
}

// Round 12
// 195.921 us; speedup vs baseline: 1.9743x; 1.1149x over previous
//
#include <hip/hip_runtime.h>

#define S_  512
#define F_  64
#define H_  32
#define GQ  128   // 4*H
#define BT  8     // real batch rows per block
#define NB  256   // 2048/BT -> one block per CU

#define XS  72    // x plane row stride (ushorts)
#define HS  40    // h plane row stride (ushorts)
#define ZS  20    // xz plane row stride (floats): (5*row+kg)&7 uniform
#define GS  33    // head buffer row stride (floats)

typedef __attribute__((ext_vector_type(8))) short bf16x8;
typedef __attribute__((ext_vector_type(4))) float f32x4;

// f32 -> (bf16_hi << 16) | bf16_lo, both RNE; f ~= hi + lo with ~2^-17 rel err
__device__ __forceinline__ unsigned pack_split(float f) {
    unsigned u  = __builtin_bit_cast(unsigned, f);
    unsigned hi = (u + 0x7FFFu + ((u >> 16) & 1u)) & 0xFFFF0000u;
    float    fl = f - __builtin_bit_cast(float, hi);
    unsigned ul = __builtin_bit_cast(unsigned, fl);
    unsigned lo = (ul + 0x7FFFu + ((ul >> 16) & 1u)) >> 16;
    return hi | lo;
}

// f32 -> bf16 (RNE), 4 ops
__device__ __forceinline__ unsigned short bf16_rne(float f) {
    unsigned u = __builtin_bit_cast(unsigned, f);
    return (unsigned short)((u + 0x7FFFu + ((u >> 16) & 1u)) >> 16);
}

__device__ __forceinline__ float sigm(float z) {
    return __builtin_amdgcn_rcpf(1.0f + __expf(-z));
}
__device__ __forceinline__ float tanh_f(float z) {
    return 2.0f * __builtin_amdgcn_rcpf(1.0f + __expf(-2.0f * z)) - 1.0f;
}

#define MFMA(A, B, C) __builtin_amdgcn_mfma_f32_16x16x32_bf16(A, B, C, 0, 0, 0)

// Producer-consumer: waves 0-7 (rec) run the h-recurrence at setprio(1);
// waves 8-15 (helpers) stage/pack x and produce xz = bias + x@Wx one DSTEP
// ahead. h stored hi-only (bf16); Wh-lo term kept via register-resident whl_.
__global__ __launch_bounds__(1024, 1)
void lstm_mfma_kernel(const float* __restrict__ x,  const float* __restrict__ Wx,
                      const float* __restrict__ Wh, const float* __restrict__ bg,
                      const float* __restrict__ W1, const float* __restrict__ b1,
                      const float* __restrict__ W2, const float* __restrict__ b2,
                      const float* __restrict__ Wo, const float* __restrict__ bo,
                      float* __restrict__ out)
{
    const int tid = threadIdx.x;     // 0..1023
    const int w   = tid >> 6;        // wave id 0..15
    const int L   = tid & 63;
    const int c16 = L & 15;          // B col: batch(0..7) + 8*dt / D col
    const int kg  = L >> 4;          // k-group AND unit-offset of D rows
    const int bb  = blockIdx.x * BT;
    const bool isRec = (w < 8);
    const int g   = w & 7;           // gate group (rec: consumes; helper: produces)
    const int jj  = (g << 2) + kg;   // hidden unit owned (rec lanes)

    // A row m -> weight column: gcol(m) = (m&3)*32 + 4g + (m>>2)
    const int gcol = ((c16 & 3) << 5) + (g << 2) + (c16 >> 2);

    __shared__ __align__(16) unsigned short xh[4][16][XS], xl[4][16][XS];
    __shared__ __align__(16) unsigned short hh[2][16][HS];   // h hi-plane only
    __shared__ __align__(16) float xzg[2][8][16][ZS];        // xz per group, dbuf
    __shared__ float Hd[3][BT][GS];

    // ---- role-specific register-resident weights ----
    bf16x8 whh_ = {0,0,0,0,0,0,0,0}, whl_ = {0,0,0,0,0,0,0,0};
    bf16x8 wx0h = {0,0,0,0,0,0,0,0}, wx0l = {0,0,0,0,0,0,0,0};
    bf16x8 wx1h = {0,0,0,0,0,0,0,0}, wx1l = {0,0,0,0,0,0,0,0};
    f32x4 biasC = {0.f, 0.f, 0.f, 0.f};
    if (isRec) {
#pragma unroll
        for (int i = 0; i < 8; ++i) {
            unsigned p = pack_split(Wh[(kg * 8 + i) * GQ + gcol]);
            whh_[i] = (short)(unsigned short)(p >> 16);
            whl_[i] = (short)(unsigned short)(p & 0xFFFFu);
        }
    } else {
#pragma unroll
        for (int i = 0; i < 8; ++i) {
            unsigned p = pack_split(Wx[(kg * 8 + i) * GQ + gcol]);
            wx0h[i] = (short)(unsigned short)(p >> 16);
            wx0l[i] = (short)(unsigned short)(p & 0xFFFFu);
            p = pack_split(Wx[(32 + kg * 8 + i) * GQ + gcol]);
            wx1h[i] = (short)(unsigned short)(p >> 16);
            wx1l[i] = (short)(unsigned short)(p & 0xFFFFu);
        }
#pragma unroll
        for (int r = 0; r < 4; ++r) biasC[r] = bg[r * 32 + jj];
    }

    // ---- zero h plane (rows 8..15 stay zero forever) ----
    for (int i = tid; i < 2 * 16 * (HS / 2); i += 1024)
        ((unsigned*)&hh[0][0][0])[i] = 0u;

    // helper staging map: row = batch(0..7) + 8*dt, feature pair
    const int hu   = tid & 511;
    const int srow = hu >> 5;        // 0..15
    const int sfp  = hu & 31;        // feature pair
    const int sdt  = srow >> 3;      // dt 0/1
    const float* xsrc = x + (size_t)(bb + (srow & 7)) * S_ * F_ + 2 * sfp;
    float2 xvA = {0.f, 0.f}, xvB = {0.f, 0.f};
    if (!isRec) {
        float2 v0 = *(const float2*)(xsrc + (size_t)(0 + sdt) * F_);
        float2 v1 = *(const float2*)(xsrc + (size_t)(2 + sdt) * F_);
        unsigned p0 = pack_split(v0.x), p1 = pack_split(v0.y);
        *(unsigned*)&xh[0][srow][2 * sfp] = (p0 >> 16) | (p1 & 0xFFFF0000u);
        *(unsigned*)&xl[0][srow][2 * sfp] = (p0 & 0xFFFFu) | (p1 << 16);
        p0 = pack_split(v1.x); p1 = pack_split(v1.y);
        *(unsigned*)&xh[1][srow][2 * sfp] = (p0 >> 16) | (p1 & 0xFFFF0000u);
        *(unsigned*)&xl[1][srow][2 * sfp] = (p0 & 0xFFFFu) | (p1 << 16);
        xvA = *(const float2*)(xsrc + (size_t)(4 + sdt) * F_);
        xvB = *(const float2*)(xsrc + (size_t)(6 + sdt) * F_);
    }
    __syncthreads();

#define XGEMM(XSLOT, ZSLOT) {                                                  \
        const int xs_ = (XSLOT);                                               \
        bf16x8 bx0h = *(const bf16x8*)&xh[xs_][c16][kg * 8];                   \
        bf16x8 bx0l = *(const bf16x8*)&xl[xs_][c16][kg * 8];                   \
        bf16x8 bx1h = *(const bf16x8*)&xh[xs_][c16][32 + kg * 8];              \
        bf16x8 bx1l = *(const bf16x8*)&xl[xs_][c16][32 + kg * 8];              \
        f32x4 a1 = {0.f, 0.f, 0.f, 0.f};                                       \
        f32x4 a2 = {0.f, 0.f, 0.f, 0.f};                                       \
        f32x4 a0 = MFMA(wx0h, bx0h, biasC);                                    \
        a1 = MFMA(wx0h, bx0l, a1);                                             \
        a2 = MFMA(wx0l, bx0h, a2);                                             \
        a0 = MFMA(wx1h, bx1h, a0);                                             \
        a1 = MFMA(wx1h, bx1l, a1);                                             \
        a2 = MFMA(wx1l, bx1h, a2);                                             \
        f32x4 xz_ = (a0 + a1) + a2;                                            \
        *(f32x4*)&xzg[(ZSLOT)][g][c16][kg << 2] = xz_;                         \
    }

    // pre-loop: helpers produce xz[0]
    if (!isRec) XGEMM(0, 0)
    __syncthreads();

    // rec waves get scheduler priority for the serial recurrence chain
    if (isRec) __builtin_amdgcn_s_setprio(1);

    float cc = 0.0f;

#define DSTEP(TD, XV) {                                                        \
    const int td = (TD);                                                       \
    f32x4 xz2 = {0.f, 0.f, 0.f, 0.f};                                          \
    if (isRec) {                                                               \
        f32x4 xzv = *(const f32x4*)&xzg[td & 1][g][c16][kg << 2];              \
        xz2 = *(const f32x4*)&xzg[td & 1][g][c16 ^ 8][kg << 2];                \
        bf16x8 bhh = *(const bf16x8*)&hh[1][c16][kg * 8];                      \
        f32x4 a2 = {0.f, 0.f, 0.f, 0.f};                                       \
        f32x4 a0 = MFMA(whh_, bhh, xzv);                                       \
        a2 = MFMA(whl_, bhh, a2);                                              \
        f32x4 z = a0 + a2;                                                     \
        float iv = sigm(z[0]), fv = sigm(z[1]);                                \
        float gv = tanh_f(z[2]), ov = sigm(z[3]);                              \
        cc = fmaf(fv, cc, iv * gv);                                            \
        float hv = ov * tanh_f(cc);                                            \
        if (c16 < 8) hh[0][c16][jj] = bf16_rne(hv);                            \
    } else {                                                                   \
        XGEMM((td + 1) & 3, (td + 1) & 1)                                      \
    }                                                                          \
    __syncthreads();   /* A: h[2td] + xz[td+1] visible */                      \
    if (isRec) {                                                               \
        bf16x8 bhh = *(const bf16x8*)&hh[0][c16][kg * 8];                      \
        f32x4 a2 = {0.f, 0.f, 0.f, 0.f};                                       \
        f32x4 a0 = MFMA(whh_, bhh, xz2);                                       \
        a2 = MFMA(whl_, bhh, a2);                                              \
        f32x4 z = a0 + a2;                                                     \
        float iv = sigm(z[0]), fv = sigm(z[1]);                                \
        float gv = tanh_f(z[2]), ov = sigm(z[3]);                              \
        cc = fmaf(fv, cc, iv * gv);                                            \
        float hv = ov * tanh_f(cc);                                            \
        if (c16 < 8) {                                                         \
            hh[1][c16][jj] = bf16_rne(hv);                                     \
            if (td == 255) Hd[0][c16][jj] = hv;                                \
        }                                                                      \
    } else {                                                                   \
        unsigned p0 = pack_split(XV.x), p1 = pack_split(XV.y);                 \
        const int s2 = (td + 2) & 3;                                           \
        *(unsigned*)&xh[s2][srow][2 * sfp] = (p0 >> 16) | (p1 & 0xFFFF0000u);  \
        *(unsigned*)&xl[s2][srow][2 * sfp] = (p0 & 0xFFFFu) | (p1 << 16);      \
        int tl = td + 4; if (tl > 255) tl = 255;                               \
        XV = *(const float2*)(xsrc + (size_t)(2 * tl + sdt) * F_);             \
    }                                                                          \
    __syncthreads();   /* B: h[2td+1] + staged x visible */                    \
}

    for (int qd = 0; qd < 128; ++qd) {
        DSTEP(2 * qd,     xvA)
        DSTEP(2 * qd + 1, xvB)
    }
#undef DSTEP
#undef XGEMM

    if (isRec) __builtin_amdgcn_s_setprio(0);

    // ---- MLP head: 32 -> 32 -> 16 -> 3, leaky_relu(0.01) ----
    if (tid < 256) {
        int rb = tid >> 5, n = tid & 31;
        float a = b1[n];
#pragma unroll
        for (int k = 0; k < 32; ++k) a = fmaf(Hd[0][rb][k], W1[k * 32 + n], a);
        a = (a > 0.0f) ? a : 0.01f * a;
        Hd[1][rb][n] = a;
    }
    __syncthreads();
    if (tid < 128) {
        int rb = tid >> 4, n = tid & 15;
        float a = b2[n];
#pragma unroll
        for (int k = 0; k < 32; ++k) a = fmaf(Hd[1][rb][k], W2[k * 16 + n], a);
        a = (a > 0.0f) ? a : 0.01f * a;
        Hd[2][rb][n] = a;
    }
    __syncthreads();
    if (tid < 24) {
        int rb = tid / 3, n = tid - rb * 3;
        float a = bo[n];
#pragma unroll
        for (int k = 0; k < 16; ++k) a = fmaf(Hd[2][rb][k], Wo[k * 3 + n], a);
        out[(size_t)(bb + rb) * 3 + n] = a;
    }
}

extern "C" void kernel_launch(void* const* d_in, const int* in_sizes, int n_in,
                              void* d_out, int out_size, void* d_ws, size_t ws_size,
                              hipStream_t stream) {
    const float* x  = (const float*)d_in[0];
    const float* Wx = (const float*)d_in[1];
    const float* Wh = (const float*)d_in[2];
    const float* bg = (const float*)d_in[3];
    const float* W1 = (const float*)d_in[4];
    const float* b1 = (const float*)d_in[5];
    const float* W2 = (const float*)d_in[6];
    const float* b2 = (const float*)d_in[7];
    const float* Wo = (const float*)d_in[8];
    const float* bo = (const float*)d_in[9];
    float* out = (float*)d_out;

    hipLaunchKernelGGL(lstm_mfma_kernel, dim3(NB), dim3(1024), 0, stream,
                       x, Wx, Wh, bg, W1, b1, W2, b2, Wo, bo, out);
}

// Round 13
// 169.591 us; speedup vs baseline: 2.2809x; 1.1553x over previous
//
#include <hip/hip_runtime.h>

#define S_  512
#define F_  64
#define H_  32
#define GQ  128   // 4*H
#define BT  8     // real batch rows per block
#define NB  256   // 2048/BT -> one block per CU

#define XS  72    // x plane row stride (ushorts)
#define HS  40    // h plane row stride (ushorts)
#define GS  33    // head buffer row stride (floats)

typedef __attribute__((ext_vector_type(8))) short bf16x8;
typedef __attribute__((ext_vector_type(4))) float f32x4;

// f32 -> (bf16_hi << 16) | bf16_lo, both RNE
__device__ __forceinline__ unsigned pack_split(float f) {
    unsigned u  = __builtin_bit_cast(unsigned, f);
    unsigned hi = (u + 0x7FFFu + ((u >> 16) & 1u)) & 0xFFFF0000u;
    float    fl = f - __builtin_bit_cast(float, hi);
    unsigned ul = __builtin_bit_cast(unsigned, fl);
    unsigned lo = (ul + 0x7FFFu + ((ul >> 16) & 1u)) >> 16;
    return hi | lo;
}

// f32 -> bf16 (RNE)
__device__ __forceinline__ unsigned short bf16_rne(float f) {
    unsigned u = __builtin_bit_cast(unsigned, f);
    return (unsigned short)((u + 0x7FFFu + ((u >> 16) & 1u)) >> 16);
}

__device__ __forceinline__ float sigm(float z) {
    return __builtin_amdgcn_rcpf(1.0f + __expf(-z));
}
__device__ __forceinline__ float tanh_f(float z) {
    return 2.0f * __builtin_amdgcn_rcpf(1.0f + __expf(-2.0f * z)) - 1.0f;
}

#define MFMA(A, B, C) __builtin_amdgcn_mfma_f32_16x16x32_bf16(A, B, C, 0, 0, 0)

// 8 homogeneous waves. Transposed MFMA, time-packed (B col = batch + 8*dt).
// Per DSTEP td: rec(2td) with reg xzA; XGEMM(td+1) -> regs; barrier;
// rec(2td+1) with reg xz1s; stage x[td+2]; barrier. xz never touches LDS.
// x stored bf16-hi only; h stored bf16-hi only; weight lo-terms kept in regs.
__global__ __launch_bounds__(512, 1)
void lstm_mfma_kernel(const float* __restrict__ x,  const float* __restrict__ Wx,
                      const float* __restrict__ Wh, const float* __restrict__ bg,
                      const float* __restrict__ W1, const float* __restrict__ b1,
                      const float* __restrict__ W2, const float* __restrict__ b2,
                      const float* __restrict__ Wo, const float* __restrict__ bo,
                      float* __restrict__ out)
{
    const int tid = threadIdx.x;     // 0..511
    const int w   = tid >> 6;        // wave id 0..7
    const int L   = tid & 63;
    const int c16 = L & 15;          // B col: batch(0..7) + 8*dt / D col
    const int kg  = L >> 4;          // k-group AND unit-offset of D rows
    const int bb  = blockIdx.x * BT;
    const int jj  = (w << 2) + kg;   // hidden unit owned by this lane

    // A row m=c16 -> weight column
    const int gcol = ((c16 & 3) << 5) + (w << 2) + (c16 >> 2);

    __shared__ __align__(16) unsigned short xh[4][16][XS];   // x hi-plane ring
    __shared__ __align__(16) unsigned short hh[2][16][HS];   // h hi-plane, parity
    __shared__ float Hd[3][BT][GS];

    // ---- register-resident weights (hi+lo) ----
    bf16x8 whh_, whl_, wx0h, wx0l, wx1h, wx1l;
#pragma unroll
    for (int i = 0; i < 8; ++i) {
        unsigned p = pack_split(Wx[(kg * 8 + i) * GQ + gcol]);
        wx0h[i] = (short)(unsigned short)(p >> 16);
        wx0l[i] = (short)(unsigned short)(p & 0xFFFFu);
        p = pack_split(Wx[(32 + kg * 8 + i) * GQ + gcol]);
        wx1h[i] = (short)(unsigned short)(p >> 16);
        wx1l[i] = (short)(unsigned short)(p & 0xFFFFu);
        p = pack_split(Wh[(kg * 8 + i) * GQ + gcol]);
        whh_[i] = (short)(unsigned short)(p >> 16);
        whl_[i] = (short)(unsigned short)(p & 0xFFFFu);
    }
    f32x4 biasC;
#pragma unroll
    for (int r = 0; r < 4; ++r) biasC[r] = bg[r * 32 + jj];
    const f32x4 zeroC = {0.f, 0.f, 0.f, 0.f};

    // ---- zero h planes (rows 8..15 stay zero forever) ----
    for (int i = tid; i < 2 * 16 * (HS / 2); i += 512)
        ((unsigned*)&hh[0][0][0])[i] = 0u;

    // staging map: row = batch(0..7) + 8*dt, feature pair; 1 u32 write per lane
    const int srow = tid >> 5;       // 0..15
    const int sfp  = tid & 31;       // feature pair
    const int sdt  = srow >> 3;      // dt 0/1
    const float* xsrc = x + (size_t)(bb + (srow & 7)) * S_ * F_ + 2 * sfp;
    {
#pragma unroll
        for (int tt = 0; tt < 2; ++tt) {
            float2 v = *(const float2*)(xsrc + (size_t)(2 * tt + sdt) * F_);
            *(unsigned*)&xh[tt][srow][2 * sfp] =
                (unsigned)bf16_rne(v.x) | ((unsigned)bf16_rne(v.y) << 16);
        }
    }
    float2 xvA = *(const float2*)(xsrc + (size_t)(4 + sdt) * F_);   // slot 2
    float2 xvB = *(const float2*)(xsrc + (size_t)(6 + sdt) * F_);   // slot 3
    __syncthreads();

    // initial XGEMM (td=0) from slot 0 -> registers
    f32x4 xzA, xz1s;
    {
        bf16x8 bxh0 = *(const bf16x8*)&xh[0][c16][kg * 8];
        bf16x8 bxh1 = *(const bf16x8*)&xh[0][c16][32 + kg * 8];
        f32x4 b0 = MFMA(wx0h, bxh0, biasC);
        f32x4 b2 = MFMA(wx0l, bxh0, zeroC);
        b0 = MFMA(wx1h, bxh1, b0);
        b2 = MFMA(wx1l, bxh1, b2);
        f32x4 xs = b0 + b2;
        xzA = xs;
#pragma unroll
        for (int r = 0; r < 4; ++r) xz1s[r] = __shfl_xor(xs[r], 8);
    }

    float cc = 0.0f;

#define DSTEP(TD, XV) {                                                        \
    const int td = (TD);                                                       \
    int tl = td + 4; if (tl > 255) tl = 255;                                   \
    float2 xnext = *(const float2*)(xsrc + (size_t)(2 * tl + sdt) * F_);       \
    /* phase 1: rec step 2td (h[2td-1] in plane 1) */                          \
    bf16x8 bhh = *(const bf16x8*)&hh[1][c16][kg * 8];                          \
    f32x4 a0 = MFMA(whh_, bhh, xzA);                                           \
    f32x4 a2 = MFMA(whl_, bhh, zeroC);                                         \
    f32x4 z = a0 + a2;                                                         \
    float iv = sigm(z[0]), fv = sigm(z[1]);                                    \
    float gv = tanh_f(z[2]), ov = sigm(z[3]);                                  \
    cc = fmaf(fv, cc, iv * gv);                                                \
    float hv = ov * tanh_f(cc);                                                \
    if (c16 < 8) hh[0][c16][jj] = bf16_rne(hv);                                \
    /* XGEMM(td+1) from slot (td+1)&3 -> next regs (independent of h) */       \
    f32x4 xzA_n, xz1s_n;                                                       \
    {                                                                          \
        const int s1 = (td + 1) & 3;                                           \
        bf16x8 bxh0 = *(const bf16x8*)&xh[s1][c16][kg * 8];                    \
        bf16x8 bxh1 = *(const bf16x8*)&xh[s1][c16][32 + kg * 8];               \
        f32x4 b0 = MFMA(wx0h, bxh0, biasC);                                    \
        f32x4 b2 = MFMA(wx0l, bxh0, zeroC);                                    \
        b0 = MFMA(wx1h, bxh1, b0);                                             \
        b2 = MFMA(wx1l, bxh1, b2);                                             \
        f32x4 xs = b0 + b2;                                                    \
        xzA_n = xs;                                                            \
        _Pragma("unroll")                                                      \
        for (int r = 0; r < 4; ++r) xz1s_n[r] = __shfl_xor(xs[r], 8);          \
    }                                                                          \
    __syncthreads();   /* A: h[2td] visible */                                 \
    /* phase 2: rec step 2td+1 (h[2td] in plane 0) */                          \
    bhh = *(const bf16x8*)&hh[0][c16][kg * 8];                                 \
    a0 = MFMA(whh_, bhh, xz1s);                                                \
    a2 = MFMA(whl_, bhh, zeroC);                                               \
    z = a0 + a2;                                                               \
    iv = sigm(z[0]); fv = sigm(z[1]);                                          \
    gv = tanh_f(z[2]); ov = sigm(z[3]);                                        \
    cc = fmaf(fv, cc, iv * gv);                                                \
    hv = ov * tanh_f(cc);                                                      \
    if (c16 < 8) {                                                             \
        hh[1][c16][jj] = bf16_rne(hv);                                         \
        if (td == 255) Hd[0][c16][jj] = hv;                                    \
    }                                                                          \
    /* stage slot td+2 from XV; reload XV for td+4 */                          \
    *(unsigned*)&xh[(td + 2) & 3][srow][2 * sfp] =                             \
        (unsigned)bf16_rne(XV.x) | ((unsigned)bf16_rne(XV.y) << 16);           \
    XV = xnext;                                                                \
    xzA = xzA_n; xz1s = xz1s_n;                                                \
    __syncthreads();   /* B: h[2td+1] + slot td+2 visible */                   \
}

    for (int qd = 0; qd < 128; ++qd) {
        DSTEP(2 * qd,     xvA)
        DSTEP(2 * qd + 1, xvB)
    }
#undef DSTEP

    __syncthreads();

    // ---- MLP head: 32 -> 32 -> 16 -> 3, leaky_relu(0.01) ----
    if (tid < 256) {
        int rb = tid >> 5, n = tid & 31;
        float a = b1[n];
#pragma unroll
        for (int k = 0; k < 32; ++k) a = fmaf(Hd[0][rb][k], W1[k * 32 + n], a);
        a = (a > 0.0f) ? a : 0.01f * a;
        Hd[1][rb][n] = a;
    }
    __syncthreads();
    if (tid < 128) {
        int rb = tid >> 4, n = tid & 15;
        float a = b2[n];
#pragma unroll
        for (int k = 0; k < 32; ++k) a = fmaf(Hd[1][rb][k], W2[k * 16 + n], a);
        a = (a > 0.0f) ? a : 0.01f * a;
        Hd[2][rb][n] = a;
    }
    __syncthreads();
    if (tid < 24) {
        int rb = tid / 3, n = tid - rb * 3;
        float a = bo[n];
#pragma unroll
        for (int k = 0; k < 16; ++k) a = fmaf(Hd[2][rb][k], Wo[k * 3 + n], a);
        out[(size_t)(bb + rb) * 3 + n] = a;
    }
}

extern "C" void kernel_launch(void* const* d_in, const int* in_sizes, int n_in,
                              void* d_out, int out_size, void* d_ws, size_t ws_size,
                              hipStream_t stream) {
    const float* x  = (const float*)d_in[0];
    const float* Wx = (const float*)d_in[1];
    const float* Wh = (const float*)d_in[2];
    const float* bg = (const float*)d_in[3];
    const float* W1 = (const float*)d_in[4];
    const float* b1 = (const float*)d_in[5];
    const float* W2 = (const float*)d_in[6];
    const float* b2 = (const float*)d_in[7];
    const float* Wo = (const float*)d_in[8];
    const float* bo = (const float*)d_in[9];
    float* out = (float*)d_out;

    hipLaunchKernelGGL(lstm_mfma_kernel, dim3(NB), dim3(512), 0, stream,
                       x, Wx, Wh, bg, W1, b1, W2, b2, Wo, bo, out);
}